// Round 3
// baseline (78.242 us; speedup 1.0000x reference)
//
#include <hip/hip_runtime.h>
#include <math.h>

constexpr int B = 256, STEP = 32, DF = 256, DZ = 64;
constexpr int TI = 8;                 // i-tile per k_z block
constexpr int NBLK_Z = (B / TI) * STEP;  // 1024
#define LOG_2PI 1.837877066409345f
#define LOG_C   16.36495572888985f    // log(256 * 50000)

__device__ __forceinline__ float warpReduceSum64(float v) {
    for (int o = 32; o > 0; o >>= 1) v += __shfl_down(v, o, 64);
    return v;
}

// 256-thread block reductions; lds4 = float[4]; result valid in ALL threads.
__device__ __forceinline__ float blockReduceSum256(float v, float* lds4) {
    int wid = threadIdx.x >> 6, lane = threadIdx.x & 63;
    v = warpReduceSum64(v);
    if (lane == 0) lds4[wid] = v;
    __syncthreads();
    float r = lds4[0] + lds4[1] + lds4[2] + lds4[3];
    __syncthreads();
    return r;
}

// 512-thread block reductions; lds8 = float[8].
__device__ __forceinline__ float blockReduceSum512(float v, float* lds8) {
    int wid = threadIdx.x >> 6, lane = threadIdx.x & 63;
    v = warpReduceSum64(v);
    if (lane == 0) lds8[wid] = v;
    __syncthreads();
    float r = 0.0f;
#pragma unroll
    for (int k = 0; k < 8; ++k) r += lds8[k];
    __syncthreads();
    return r;
}
__device__ __forceinline__ float blockReduceMax512(float v, float* lds8) {
    int wid = threadIdx.x >> 6, lane = threadIdx.x & 63;
    for (int o = 32; o > 0; o >>= 1) v = fmaxf(v, __shfl_down(v, o, 64));
    if (lane == 0) lds8[wid] = v;
    __syncthreads();
    float r = -INFINITY;
#pragma unroll
    for (int k = 0; k < 8; ++k) r = fmaxf(r, lds8[k]);
    __syncthreads();
    return r;
}

// Self-contained f kernel: computes e=exp(-lv) and wcf on the fly (thread j owns row j).
// grid = B (i), block = 512 (t = half*256 + j); each thread does 128 dims.
__global__ void k_f(const float* __restrict__ fm, const float* __restrict__ fl,
                    const float* __restrict__ fs,
                    float* __restrict__ sum_f, float* __restrict__ hneg_f,
                    int* __restrict__ counter) {
    int i = blockIdx.x, t = threadIdx.x;
    int j = t & (B - 1), half = t >> 8;
    __shared__ float fs_sh[DF];
    __shared__ float pacc[2][B];
    __shared__ float pwc[2][B];
    __shared__ float lds8[8];
    if (t < DF) fs_sh[t] = fs[(size_t)i * DF + t];
    if (t == 0 && i == 0) *counter = 0;   // reset for k_z's last-block detection
    __syncthreads();

    const float4* fm4 = reinterpret_cast<const float4*>(fm + (size_t)j * DF) + half * 32;
    const float4* fl4 = reinterpret_cast<const float4*>(fl + (size_t)j * DF) + half * 32;
    const float4* fs4 = reinterpret_cast<const float4*>(fs_sh) + half * 32;
    float acc = 0.0f, wcl = 0.0f;
#pragma unroll 8
    for (int k = 0; k < DF / 8; ++k) {   // 32 chunks of 4 dims
        float4 lv = fl4[k], m4 = fm4[k], sv = fs4[k];
        float e0 = __expf(-lv.x), e1 = __expf(-lv.y);
        float e2 = __expf(-lv.z), e3 = __expf(-lv.w);
        wcl += (lv.x + lv.y) + (lv.z + lv.w);
        float t0 = (sv.x - m4.x) * e0;
        float t1 = (sv.y - m4.y) * e1;
        float t2 = (sv.z - m4.z) * e2;
        float t3 = (sv.w - m4.w) * e3;
        acc = fmaf(t0, t0, acc); acc = fmaf(t1, t1, acc);
        acc = fmaf(t2, t2, acc); acc = fmaf(t3, t3, acc);
    }
    pacc[half][j] = acc;
    pwc[half][j]  = wcl;
    __syncthreads();

    float val = -INFINITY;
    if (t < B) {
        val = -0.5f * (pacc[0][j] + pacc[1][j]
                       + 2.0f * (pwc[0][j] + pwc[1][j]) + (float)DF * LOG_2PI);
        sum_f[(size_t)i * B + j] = val;
    }
    float m = blockReduceMax512(val, lds8);
    float ssum = blockReduceSum512(t < B ? __expf(val - m) : 0.0f, lds8);
    if (t == 0) {
        float logq = m + __logf(ssum) - LOG_C;
        hneg_f[i] = fmaxf(-logq, 0.0f);
    }
}

// Self-contained z kernel + fused final reduction (deterministic last-block pattern).
// grid = (B/TI, STEP), block = 256 (j). Reads zm/zl/zs in ORIGINAL [B,STEP,DZ] layout.
__global__ void k_z(const float* __restrict__ zm, const float* __restrict__ zl,
                    const float* __restrict__ zs,
                    const float* __restrict__ sum_f, const float* __restrict__ hneg_f,
                    float* __restrict__ partials, int* __restrict__ counter,
                    float* __restrict__ out) {
    int it = blockIdx.x, s = blockIdx.y, j = threadIdx.x;
    int i0 = it * TI;
    int bid = blockIdx.y * gridDim.x + blockIdx.x;
    __shared__ float zs_sh[TI][DZ];    // 2 KB
    __shared__ float red[2][TI][B];    // 16 KB
    __shared__ float hbuf[2 * TI];
    __shared__ float lds4[4];
    __shared__ int   is_last;

    // Stage TI sample rows from original layout (row (i,s) is contiguous 256 B).
    if (j < TI * DZ / 4) {
        int i = j >> 4, c = j & 15;
        float4 v = *reinterpret_cast<const float4*>(
            &zs[((size_t)(i0 + i) * STEP + s) * DZ + c * 4]);
        *reinterpret_cast<float4*>(&zs_sh[i][c * 4]) = v;
    }
    __syncthreads();

    const float4* zm4 = reinterpret_cast<const float4*>(zm + ((size_t)j * STEP + s) * DZ);
    const float4* zl4 = reinterpret_cast<const float4*>(zl + ((size_t)j * STEP + s) * DZ);
    float acc[TI];
#pragma unroll
    for (int i = 0; i < TI; ++i) acc[i] = 0.0f;
    float wcl = 0.0f;
#pragma unroll
    for (int k = 0; k < DZ / 4; ++k) {
        float4 lv = zl4[k], m4 = zm4[k];
        float e0 = __expf(-lv.x), e1 = __expf(-lv.y);
        float e2 = __expf(-lv.z), e3 = __expf(-lv.w);
        wcl += (lv.x + lv.y) + (lv.z + lv.w);
        float me0 = m4.x * e0, me1 = m4.y * e1, me2 = m4.z * e2, me3 = m4.w * e3;
#pragma unroll
        for (int i = 0; i < TI; ++i) {
            float4 sv = *reinterpret_cast<const float4*>(&zs_sh[i][k * 4]);
            float t0 = fmaf(sv.x, e0, -me0);
            float t1 = fmaf(sv.y, e1, -me1);
            float t2 = fmaf(sv.z, e2, -me2);
            float t3 = fmaf(sv.w, e3, -me3);
            acc[i] = fmaf(t0, t0, acc[i]);
            acc[i] = fmaf(t1, t1, acc[i]);
            acc[i] = fmaf(t2, t2, acc[i]);
            acc[i] = fmaf(t3, t3, acc[i]);
        }
    }
    float wcj = 2.0f * wcl + (float)DZ * LOG_2PI;
#pragma unroll
    for (int i = 0; i < TI; ++i) {
        float sz = -0.5f * (acc[i] + wcj);
        red[0][i][j] = sz;
        red[1][i][j] = sz + sum_f[(size_t)(i0 + i) * B + j];
    }
    __syncthreads();

    // 16 LSE tasks (TI i's x {z, fz}); wave w handles tasks 4w..4w+3.
    int wave = j >> 6, lane = j & 63;
#pragma unroll
    for (int t = 0; t < 4; ++t) {
        int task = wave * 4 + t;
        int type = task & 1, i = task >> 1;
        float v0 = red[type][i][lane];
        float v1 = red[type][i][lane + 64];
        float v2 = red[type][i][lane + 128];
        float v3 = red[type][i][lane + 192];
        float m = fmaxf(fmaxf(v0, v1), fmaxf(v2, v3));
        for (int o = 32; o > 0; o >>= 1) m = fmaxf(m, __shfl_xor(m, o, 64));
        float ssum = __expf(v0 - m) + __expf(v1 - m) + __expf(v2 - m) + __expf(v3 - m);
        for (int o = 32; o > 0; o >>= 1) ssum += __shfl_xor(ssum, o, 64);
        if (lane == 0) {
            float lq = m + __logf(ssum) - LOG_C;
            hbuf[task] = fmaxf(-lq, 0.0f);
        }
    }
    __syncthreads();

    // Per-block partial sums (fixed order -> deterministic), then counter.
    if (j == 0) {
        float pz = 0.0f, pfz = 0.0f;
#pragma unroll
        for (int i = 0; i < TI; ++i) { pz += hbuf[2 * i]; pfz += hbuf[2 * i + 1]; }
        __hip_atomic_store(&partials[2 * bid], pz, __ATOMIC_RELAXED, __HIP_MEMORY_SCOPE_AGENT);
        __hip_atomic_store(&partials[2 * bid + 1], pfz, __ATOMIC_RELAXED, __HIP_MEMORY_SCOPE_AGENT);
        __threadfence();
        int old = atomicAdd(counter, 1);
        is_last = (old == NBLK_Z - 1) ? 1 : 0;
    }
    __syncthreads();

    if (is_last) {
        __threadfence();
        float pz = 0.0f, pfz = 0.0f;
#pragma unroll
        for (int r = 0; r < NBLK_Z / B; ++r) {     // 4 per thread
            int b = r * B + j;
            pz  += __hip_atomic_load(&partials[2 * b], __ATOMIC_RELAXED, __HIP_MEMORY_SCOPE_AGENT);
            pfz += __hip_atomic_load(&partials[2 * b + 1], __ATOMIC_RELAXED, __HIP_MEMORY_SCOPE_AGENT);
        }
        float hf = hneg_f[j];
        float Hz  = blockReduceSum256(pz, lds4) * (1.0f / (STEP * B));
        float Hfz = blockReduceSum256(pfz, lds4) * (1.0f / (STEP * B));
        float Hf  = blockReduceSum256(hf, lds4) * (1.0f / B);
        if (j == 0) out[0] = Hf + Hz - Hfz;
    }
}

extern "C" void kernel_launch(void* const* d_in, const int* in_sizes, int n_in,
                              void* d_out, int out_size, void* d_ws, size_t ws_size,
                              hipStream_t stream) {
    const float* f_mean   = (const float*)d_in[0];
    const float* f_logvar = (const float*)d_in[1];
    const float* f_sample = (const float*)d_in[2];
    const float* z_mean   = (const float*)d_in[3];
    const float* z_logvar = (const float*)d_in[4];
    const float* z_sample = (const float*)d_in[5];
    float* out = (float*)d_out;

    float* w = (float*)d_ws;
    float* sum_f    = w;  w += B * B;        // 65536
    float* hneg_f   = w;  w += B;            // 256
    float* partials = w;  w += 2 * NBLK_Z;   // 2048
    int*   counter  = (int*)w;

    k_f<<<dim3(B), dim3(512), 0, stream>>>(f_mean, f_logvar, f_sample,
                                           sum_f, hneg_f, counter);
    k_z<<<dim3(B / TI, STEP), dim3(B), 0, stream>>>(z_mean, z_logvar, z_sample,
                                                    sum_f, hneg_f, partials,
                                                    counter, out);
}